// Round 3
// baseline (832.122 us; speedup 1.0000x reference)
//
#include <hip/hip_runtime.h>

// out[i] = sum_{e: rows[e]==i} Param_W[params[e]] * x[cols[e]] + Param_b[b_params[i]]
// N = 262144, E = 16777216, NPARAMS = 1280, NB = 16.
//
// R11 post-mortem: fused kernel FAILED (absmax 83) due to a UNITS bug:
// FSTREAM treated b0 as a group offset (scan4 convention) while the loop
// passed batch indices -> only groups 0..35 of 128 touched, many twice.
// R12 = R11 with g = (b0*SB4 + b)*SCAN_THREADS + tid. Fusion theory stands:
// gather x (L2-resident) + PW (L1-resident) for ACTIVE edges under the 85us
// LDS-atomic stream; kill val kernel (~95us) + 134MB vals traffic + one
// kernel boundary (~25us). Predict fused ~100-130us, total ~230-260.

#define SLICE_BITS  15
#define SLICE_SIZE  (1 << SLICE_BITS)   // 32768
#define SLICES      8
#define CHUNKS      32
#define NPARAMS_MAX 2048
#define SCAN_THREADS 1024
#define SB4         4                   // int4-groups per pipeline batch
#define VB          4                   // batched groups per val-kernel thread (fallback path)

typedef float v4f __attribute__((ext_vector_type(4)));

// ---------- Kernel F: fused gather + slice-scan (single pass over edges) ----------
__global__ __launch_bounds__(SCAN_THREADS, 1) void fused_scan_kernel(
    const float* __restrict__ x, const float* __restrict__ PW,
    const int4* __restrict__ rows4, const int4* __restrict__ cols4,
    const int4* __restrict__ params4, float* __restrict__ partials,
    int e4_per_chunk)
{
    __shared__ float acc[SLICE_SIZE];    // 128 KiB -> 1 block/CU, 16 waves
    const int bid = blockIdx.x;
    const int s = bid / CHUNKS;          // slice
    const int c = bid % CHUNKS;          // chunk; bid%8==c%8 -> all 8 readers of a
                                         // chunk land on one XCD (L2 co-location)
    const int tid = threadIdx.x;
    for (int j = tid; j < SLICE_SIZE; j += SCAN_THREADS) acc[j] = 0.0f;
    __syncthreads();

    const int4* rp = rows4   + (size_t)c * e4_per_chunk;
    const int4* cp = cols4   + (size_t)c * e4_per_chunk;
    const int4* qp = params4 + (size_t)c * e4_per_chunk;
    const int per_thread = e4_per_chunk / SCAN_THREADS;  // 128 int4 groups
    const int nb = per_thread / SB4;                     // 32 batches

    // ping-pong pipeline state (all indices compile-time: no scratch)
    int4   sr0[SB4], sc0[SB4], sp0[SB4];   // stream bufs (rows, cols, params)
    int4   sr1[SB4], sc1[SB4], sp1[SB4];
    int4   r0[SB4],  r1[SB4];              // rows held until ADD
    float4 gx0[SB4], gp0[SB4];             // gathered x / PW (valid where active)
    float4 gx1[SB4], gp1[SB4];

// b0 is a BATCH index: batch j covers int4-groups [j*SB4, j*SB4+SB4)
#define FSTREAM(K, b0)                                                       \
    _Pragma("unroll")                                                        \
    for (int b = 0; b < SB4; ++b) {                                          \
        const int g = ((b0) * SB4 + b) * SCAN_THREADS + tid;                 \
        sr##K[b] = rp[g]; sc##K[b] = cp[g]; sp##K[b] = qp[g];                \
    }
// issue predicated gathers for batch in stream buf K; stash rows for ADD
#define FGATHER(K)                                                           \
    _Pragma("unroll")                                                        \
    for (int b = 0; b < SB4; ++b) {                                          \
        r##K[b] = sr##K[b];                                                  \
        if ((sr##K[b].x >> SLICE_BITS) == s) { gx##K[b].x = x[sc##K[b].x]; gp##K[b].x = PW[sp##K[b].x]; } \
        if ((sr##K[b].y >> SLICE_BITS) == s) { gx##K[b].y = x[sc##K[b].y]; gp##K[b].y = PW[sp##K[b].y]; } \
        if ((sr##K[b].z >> SLICE_BITS) == s) { gx##K[b].z = x[sc##K[b].z]; gp##K[b].z = PW[sp##K[b].z]; } \
        if ((sr##K[b].w >> SLICE_BITS) == s) { gx##K[b].w = x[sc##K[b].w]; gp##K[b].w = PW[sp##K[b].w]; } \
    }
#define FADD(K)                                                              \
    _Pragma("unroll")                                                        \
    for (int b = 0; b < SB4; ++b) {                                          \
        if ((r##K[b].x >> SLICE_BITS) == s) atomicAdd(&acc[r##K[b].x & (SLICE_SIZE - 1)], gx##K[b].x * gp##K[b].x); \
        if ((r##K[b].y >> SLICE_BITS) == s) atomicAdd(&acc[r##K[b].y & (SLICE_SIZE - 1)], gx##K[b].y * gp##K[b].y); \
        if ((r##K[b].z >> SLICE_BITS) == s) atomicAdd(&acc[r##K[b].z & (SLICE_SIZE - 1)], gx##K[b].z * gp##K[b].z); \
        if ((r##K[b].w >> SLICE_BITS) == s) atomicAdd(&acc[r##K[b].w & (SLICE_SIZE - 1)], gx##K[b].w * gp##K[b].w); \
    }

    // schedule per slot j: STREAM(j+2) | GATHER(j+1) | ADD(j)
    // -> gather latency covered by one ADD batch; stream latency by ~1.5 slots.
    FSTREAM(0, 0)
    FSTREAM(1, 1)
    FGATHER(0)
    for (int j = 0; j < nb; j += 2) {
        // slot j (even): bufs S0 free (gathered at slot j-1)
        if (j + 2 < nb) { FSTREAM(0, j + 2) }
        FGATHER(1)                          // batch j+1 (streamed 1 slot ago)
        FADD(0)                             // batch j   (gathered 1 slot ago)
        // slot j+1 (odd)
        if (j + 3 < nb) { FSTREAM(1, j + 3) }
        if (j + 2 < nb) { FGATHER(0) }      // batch j+2
        FADD(1)                             // batch j+1
    }
#undef FSTREAM
#undef FGATHER
#undef FADD

    __syncthreads();
    float* dst = partials + (size_t)bid * SLICE_SIZE;
    for (int j = tid; j < SLICE_SIZE; j += SCAN_THREADS) dst[j] = acc[j];
}

// ---------------- Kernel V: val precompute (R9 fallback path) ----------------
__global__ __launch_bounds__(256) void val_kernel(
    const float* __restrict__ x, const float* __restrict__ PW, int nparams,
    const int4* __restrict__ cols4, const int4* __restrict__ params4,
    v4f* __restrict__ vals4)
{
    __shared__ float pw[NPARAMS_MAX];
    for (int j = threadIdx.x; j < nparams; j += 256) pw[j] = PW[j];
    __syncthreads();
    const int base = blockIdx.x * (256 * VB) + threadIdx.x;
    int4 c[VB], p[VB];
#pragma unroll
    for (int k = 0; k < VB; ++k) {
        c[k] = cols4[base + k * 256];
        p[k] = params4[base + k * 256];
    }
#pragma unroll
    for (int k = 0; k < VB; ++k) {
        v4f v;
        v.x = pw[p[k].x] * x[c[k].x];
        v.y = pw[p[k].y] * x[c[k].y];
        v.z = pw[p[k].z] * x[c[k].z];
        v.w = pw[p[k].w] * x[c[k].w];
        __builtin_nontemporal_store(v, &vals4[base + k * 256]);
    }
}

// ------- Kernel S: 2-stream scan (R9 fallback path) -------
__global__ __launch_bounds__(SCAN_THREADS, 1) void scan4_kernel(
    const int4* __restrict__ rows4, const float4* __restrict__ vals4,
    float* __restrict__ partials, int e4_per_chunk)
{
    __shared__ float acc[SLICE_SIZE];
    const int bid = blockIdx.x;
    const int s = bid / CHUNKS;
    const int c = bid % CHUNKS;
    for (int j = threadIdx.x; j < SLICE_SIZE; j += SCAN_THREADS) acc[j] = 0.0f;
    __syncthreads();

    const int4*   rp = rows4 + (size_t)c * e4_per_chunk;
    const float4* vp = vals4 + (size_t)c * e4_per_chunk;
    const int per_thread = e4_per_chunk / SCAN_THREADS;

    int4   rA[SB4], rB[SB4];
    float4 vA[SB4], vB[SB4];

#define LOAD(dstR, dstV, b0)                                             \
    _Pragma("unroll")                                                    \
    for (int b = 0; b < SB4; ++b) {                                      \
        const int g = ((b0) + b) * SCAN_THREADS + (int)threadIdx.x;      \
        dstR[b] = rp[g];                                                 \
        dstV[b] = vp[g];                                                 \
    }
#define PROC(rX, vX)                                                     \
    _Pragma("unroll")                                                    \
    for (int b = 0; b < SB4; ++b) {                                      \
        if ((rX[b].x >> SLICE_BITS) == s) atomicAdd(&acc[rX[b].x & (SLICE_SIZE - 1)], vX[b].x); \
        if ((rX[b].y >> SLICE_BITS) == s) atomicAdd(&acc[rX[b].y & (SLICE_SIZE - 1)], vX[b].y); \
        if ((rX[b].z >> SLICE_BITS) == s) atomicAdd(&acc[rX[b].z & (SLICE_SIZE - 1)], vX[b].z); \
        if ((rX[b].w >> SLICE_BITS) == s) atomicAdd(&acc[rX[b].w & (SLICE_SIZE - 1)], vX[b].w); \
    }

    LOAD(rA, vA, 0)
    for (int base = 0; base < per_thread; base += 2 * SB4) {
        LOAD(rB, vB, base + SB4)
        PROC(rA, vA)
        if (base + 2 * SB4 < per_thread) {
            LOAD(rA, vA, base + 2 * SB4)
        }
        PROC(rB, vB)
    }
#undef LOAD
#undef PROC
    __syncthreads();

    float* dst = partials + (size_t)bid * SLICE_SIZE;
    for (int j = threadIdx.x; j < SLICE_SIZE; j += SCAN_THREADS) dst[j] = acc[j];
}

// ---------------- Kernel E: reduce partials + bias ----------------
__global__ __launch_bounds__(256) void reduce_bias_kernel(
    const float* __restrict__ partials, const float* __restrict__ Pb,
    const int* __restrict__ bp, float* __restrict__ out, int n)
{
    const int i = blockIdx.x * 256 + threadIdx.x;
    if (i >= n) return;
    const int s = i >> SLICE_BITS;
    const int j = i & (SLICE_SIZE - 1);
    const float* p = partials + ((size_t)s * CHUNKS) * SLICE_SIZE + j;
    float sum = 0.0f;
#pragma unroll
    for (int g = 0; g < CHUNKS; ++g) sum += p[(size_t)g * SLICE_SIZE];
    out[i] = sum + Pb[bp[i]];
}

// ---------------- last-resort fallbacks ----------------
__global__ __launch_bounds__(256) void bias_init_kernel(const float* __restrict__ Pb,
                                                        const int* __restrict__ bp,
                                                        float* __restrict__ out, int n) {
    int i = blockIdx.x * 256 + threadIdx.x;
    if (i < n) out[i] = Pb[bp[i]];
}

__global__ __launch_bounds__(256) void edge_scatter_kernel(const float* __restrict__ x,
                                                           const float* __restrict__ PW,
                                                           const int* __restrict__ rows,
                                                           const int* __restrict__ cols,
                                                           const int* __restrict__ params,
                                                           float* __restrict__ out, int E) {
    int e = blockIdx.x * 256 + threadIdx.x;
    if (e < E) atomicAdd(out + rows[e], PW[params[e]] * x[cols[e]]);
}

extern "C" void kernel_launch(void* const* d_in, const int* in_sizes, int n_in,
                              void* d_out, int out_size, void* d_ws, size_t ws_size,
                              hipStream_t stream) {
    const float* x        = (const float*)d_in[0];
    const float* Param_W  = (const float*)d_in[1];
    const float* Param_b  = (const float*)d_in[2];
    const int*   w_rows   = (const int*)d_in[3];
    const int*   w_cols   = (const int*)d_in[4];
    const int*   w_params = (const int*)d_in[5];
    const int*   b_params = (const int*)d_in[6];
    float* out = (float*)d_out;

    const int N_  = in_sizes[0];   // 262144
    const int NP_ = in_sizes[1];   // 1280
    const int E_  = in_sizes[3];   // 16777216
    const int e4  = E_ / 4;

    const size_t partial_bytes = (size_t)SLICES * CHUNKS * SLICE_SIZE * sizeof(float); // 32 MiB
    const size_t vals_bytes    = (size_t)E_ * sizeof(float);                            // 64 MiB

    const bool base_ok = (N_ == SLICES * SLICE_SIZE) && (NP_ <= NPARAMS_MAX);

    // fused single-pass path
    const bool fused_ok = base_ok && (e4 % CHUNKS == 0) &&
                          ((e4 / CHUNKS) % (SCAN_THREADS * 2 * SB4) == 0);
    // R9 two-pass path
    const bool full_ok = base_ok && (E_ % (4 * 256 * VB) == 0) &&
                         (E_ % (4 * CHUNKS * SCAN_THREADS * 2 * SB4) == 0);

    if (fused_ok && ws_size >= partial_bytes) {
        float* partials = (float*)d_ws;
        const int e4_per_chunk = e4 / CHUNKS;   // 131072
        fused_scan_kernel<<<SLICES * CHUNKS, SCAN_THREADS, 0, stream>>>(
            x, Param_W, (const int4*)w_rows, (const int4*)w_cols,
            (const int4*)w_params, partials, e4_per_chunk);
        reduce_bias_kernel<<<(N_ + 255) / 256, 256, 0, stream>>>(
            partials, Param_b, b_params, out, N_);
    } else if (full_ok && ws_size >= vals_bytes + partial_bytes) {
        float*  vals     = (float*)d_ws;
        float*  partials = (float*)((char*)d_ws + vals_bytes);
        const int e4_per_chunk = e4 / CHUNKS;
        val_kernel<<<e4 / (256 * VB), 256, 0, stream>>>(
            x, Param_W, NP_, (const int4*)w_cols, (const int4*)w_params, (v4f*)vals);
        scan4_kernel<<<SLICES * CHUNKS, SCAN_THREADS, 0, stream>>>(
            (const int4*)w_rows, (const float4*)vals, partials, e4_per_chunk);
        reduce_bias_kernel<<<(N_ + 255) / 256, 256, 0, stream>>>(
            partials, Param_b, b_params, out, N_);
    } else {
        bias_init_kernel<<<(N_ + 255) / 256, 256, 0, stream>>>(Param_b, b_params, out, N_);
        edge_scatter_kernel<<<(E_ + 255) / 256, 256, 0, stream>>>(
            x, Param_W, w_rows, w_cols, w_params, out, E_);
    }
}

// Round 4
// 370.274 us; speedup vs baseline: 2.2473x; 2.2473x over previous
//
#include <hip/hip_runtime.h>

// out[i] = sum_{e: rows[e]==i} Param_W[params[e]] * x[cols[e]] + Param_b[b_params[i]]
// N = 262144, E = 16777216, NPARAMS = 1280, NB = 16.
//
// R12 post-mortem: fused schedule was CORRECT but spilled: 16-wave block +
// 128KiB LDS -> 4 waves/SIMD -> HARD 128 VGPR cap; SB4=4 pipeline needed
// ~192 live regs -> compiler allocated 64 + ~750MB scratch round-trip
// (WRITE_SIZE 786MB, 705us). R13: SB4->2 (live state ~115 regs) +
// __launch_bounds__(1024,4) so the allocator targets the 128-VGPR budget.
// Predict: VGPR ~110-128, WRITE 786->33MB, FETCH 753->~230MB,
// fused 705 -> ~105-140us, total -> ~240-270.

#define SLICE_BITS  15
#define SLICE_SIZE  (1 << SLICE_BITS)   // 32768
#define SLICES      8
#define CHUNKS      32
#define NPARAMS_MAX 2048
#define SCAN_THREADS 1024
#define FSB         2                   // fused path: int4-groups per pipeline batch
#define SB4         4                   // scan4 fallback batch
#define VB          4                   // val fallback batch

typedef float v4f __attribute__((ext_vector_type(4)));

// ---------- Kernel F: fused gather + slice-scan (single pass over edges) ----------
__global__ __launch_bounds__(SCAN_THREADS, 4) void fused_scan_kernel(
    const float* __restrict__ x, const float* __restrict__ PW,
    const int4* __restrict__ rows4, const int4* __restrict__ cols4,
    const int4* __restrict__ params4, float* __restrict__ partials,
    int e4_per_chunk)
{
    __shared__ float acc[SLICE_SIZE];    // 128 KiB -> 1 block/CU, 16 waves
    const int bid = blockIdx.x;
    const int s = bid / CHUNKS;          // slice
    const int c = bid % CHUNKS;          // chunk; bid%8==c%8 -> all 8 readers of a
                                         // chunk land on one XCD (L2 co-location)
    const int tid = threadIdx.x;
    for (int j = tid; j < SLICE_SIZE; j += SCAN_THREADS) acc[j] = 0.0f;
    __syncthreads();

    const int4* rp = rows4   + (size_t)c * e4_per_chunk;
    const int4* cp = cols4   + (size_t)c * e4_per_chunk;
    const int4* qp = params4 + (size_t)c * e4_per_chunk;
    const int per_thread = e4_per_chunk / SCAN_THREADS;  // 128 int4 groups
    const int nb = per_thread / FSB;                     // 64 batches

    // ping-pong pipeline state, sized for the 128-VGPR/wave budget:
    // streams 2*3*FSB*4 = 48, row copies 2*FSB*4 = 16, gathers 4*FSB*4 = 32
    int4   sr0[FSB], sc0[FSB], sp0[FSB];   // stream bufs (rows, cols, params)
    int4   sr1[FSB], sc1[FSB], sp1[FSB];
    int4   r0[FSB],  r1[FSB];              // rows held until ADD
    float4 gx0[FSB], gp0[FSB];             // gathered x / PW (valid where active)
    float4 gx1[FSB], gp1[FSB];

// b0 is a BATCH index: batch j covers int4-groups [j*FSB, j*FSB+FSB)
#define FSTREAM(K, b0)                                                       \
    _Pragma("unroll")                                                        \
    for (int b = 0; b < FSB; ++b) {                                          \
        const int g = ((b0) * FSB + b) * SCAN_THREADS + tid;                 \
        sr##K[b] = rp[g]; sc##K[b] = cp[g]; sp##K[b] = qp[g];                \
    }
// issue predicated gathers for batch in stream buf K; stash rows for ADD
#define FGATHER(K)                                                           \
    _Pragma("unroll")                                                        \
    for (int b = 0; b < FSB; ++b) {                                          \
        r##K[b] = sr##K[b];                                                  \
        if ((sr##K[b].x >> SLICE_BITS) == s) { gx##K[b].x = x[sc##K[b].x]; gp##K[b].x = PW[sp##K[b].x]; } \
        if ((sr##K[b].y >> SLICE_BITS) == s) { gx##K[b].y = x[sc##K[b].y]; gp##K[b].y = PW[sp##K[b].y]; } \
        if ((sr##K[b].z >> SLICE_BITS) == s) { gx##K[b].z = x[sc##K[b].z]; gp##K[b].z = PW[sp##K[b].z]; } \
        if ((sr##K[b].w >> SLICE_BITS) == s) { gx##K[b].w = x[sc##K[b].w]; gp##K[b].w = PW[sp##K[b].w]; } \
    }
#define FADD(K)                                                              \
    _Pragma("unroll")                                                        \
    for (int b = 0; b < FSB; ++b) {                                          \
        if ((r##K[b].x >> SLICE_BITS) == s) atomicAdd(&acc[r##K[b].x & (SLICE_SIZE - 1)], gx##K[b].x * gp##K[b].x); \
        if ((r##K[b].y >> SLICE_BITS) == s) atomicAdd(&acc[r##K[b].y & (SLICE_SIZE - 1)], gx##K[b].y * gp##K[b].y); \
        if ((r##K[b].z >> SLICE_BITS) == s) atomicAdd(&acc[r##K[b].z & (SLICE_SIZE - 1)], gx##K[b].z * gp##K[b].z); \
        if ((r##K[b].w >> SLICE_BITS) == s) atomicAdd(&acc[r##K[b].w & (SLICE_SIZE - 1)], gx##K[b].w * gp##K[b].w); \
    }

    // schedule per slot j: STREAM(j+2) | GATHER(j+1) | ADD(j)
    // -> gather latency covered by one ADD batch; stream latency by ~1.5 slots.
    FSTREAM(0, 0)
    FSTREAM(1, 1)
    FGATHER(0)
    for (int j = 0; j < nb; j += 2) {
        // slot j (even): bufs S0 free (gathered at slot j-1; rows saved in r0)
        if (j + 2 < nb) { FSTREAM(0, j + 2) }
        FGATHER(1)                          // batch j+1 (streamed 1 slot ago)
        FADD(0)                             // batch j   (gathered 1 slot ago)
        // slot j+1 (odd)
        if (j + 3 < nb) { FSTREAM(1, j + 3) }
        if (j + 2 < nb) { FGATHER(0) }      // batch j+2
        FADD(1)                             // batch j+1
    }
#undef FSTREAM
#undef FGATHER
#undef FADD

    __syncthreads();
    float* dst = partials + (size_t)bid * SLICE_SIZE;
    for (int j = tid; j < SLICE_SIZE; j += SCAN_THREADS) dst[j] = acc[j];
}

// ---------------- Kernel V: val precompute (R9 fallback path) ----------------
__global__ __launch_bounds__(256) void val_kernel(
    const float* __restrict__ x, const float* __restrict__ PW, int nparams,
    const int4* __restrict__ cols4, const int4* __restrict__ params4,
    v4f* __restrict__ vals4)
{
    __shared__ float pw[NPARAMS_MAX];
    for (int j = threadIdx.x; j < nparams; j += 256) pw[j] = PW[j];
    __syncthreads();
    const int base = blockIdx.x * (256 * VB) + threadIdx.x;
    int4 c[VB], p[VB];
#pragma unroll
    for (int k = 0; k < VB; ++k) {
        c[k] = cols4[base + k * 256];
        p[k] = params4[base + k * 256];
    }
#pragma unroll
    for (int k = 0; k < VB; ++k) {
        v4f v;
        v.x = pw[p[k].x] * x[c[k].x];
        v.y = pw[p[k].y] * x[c[k].y];
        v.z = pw[p[k].z] * x[c[k].z];
        v.w = pw[p[k].w] * x[c[k].w];
        __builtin_nontemporal_store(v, &vals4[base + k * 256]);
    }
}

// ------- Kernel S: 2-stream scan (R9 fallback path) -------
__global__ __launch_bounds__(SCAN_THREADS, 1) void scan4_kernel(
    const int4* __restrict__ rows4, const float4* __restrict__ vals4,
    float* __restrict__ partials, int e4_per_chunk)
{
    __shared__ float acc[SLICE_SIZE];
    const int bid = blockIdx.x;
    const int s = bid / CHUNKS;
    const int c = bid % CHUNKS;
    for (int j = threadIdx.x; j < SLICE_SIZE; j += SCAN_THREADS) acc[j] = 0.0f;
    __syncthreads();

    const int4*   rp = rows4 + (size_t)c * e4_per_chunk;
    const float4* vp = vals4 + (size_t)c * e4_per_chunk;
    const int per_thread = e4_per_chunk / SCAN_THREADS;

    int4   rA[SB4], rB[SB4];
    float4 vA[SB4], vB[SB4];

#define LOAD(dstR, dstV, b0)                                             \
    _Pragma("unroll")                                                    \
    for (int b = 0; b < SB4; ++b) {                                      \
        const int g = ((b0) + b) * SCAN_THREADS + (int)threadIdx.x;      \
        dstR[b] = rp[g];                                                 \
        dstV[b] = vp[g];                                                 \
    }
#define PROC(rX, vX)                                                     \
    _Pragma("unroll")                                                    \
    for (int b = 0; b < SB4; ++b) {                                      \
        if ((rX[b].x >> SLICE_BITS) == s) atomicAdd(&acc[rX[b].x & (SLICE_SIZE - 1)], vX[b].x); \
        if ((rX[b].y >> SLICE_BITS) == s) atomicAdd(&acc[rX[b].y & (SLICE_SIZE - 1)], vX[b].y); \
        if ((rX[b].z >> SLICE_BITS) == s) atomicAdd(&acc[rX[b].z & (SLICE_SIZE - 1)], vX[b].z); \
        if ((rX[b].w >> SLICE_BITS) == s) atomicAdd(&acc[rX[b].w & (SLICE_SIZE - 1)], vX[b].w); \
    }

    LOAD(rA, vA, 0)
    for (int base = 0; base < per_thread; base += 2 * SB4) {
        LOAD(rB, vB, base + SB4)
        PROC(rA, vA)
        if (base + 2 * SB4 < per_thread) {
            LOAD(rA, vA, base + 2 * SB4)
        }
        PROC(rB, vB)
    }
#undef LOAD
#undef PROC
    __syncthreads();

    float* dst = partials + (size_t)bid * SLICE_SIZE;
    for (int j = threadIdx.x; j < SLICE_SIZE; j += SCAN_THREADS) dst[j] = acc[j];
}

// ---------------- Kernel E: reduce partials + bias ----------------
__global__ __launch_bounds__(256) void reduce_bias_kernel(
    const float* __restrict__ partials, const float* __restrict__ Pb,
    const int* __restrict__ bp, float* __restrict__ out, int n)
{
    const int i = blockIdx.x * 256 + threadIdx.x;
    if (i >= n) return;
    const int s = i >> SLICE_BITS;
    const int j = i & (SLICE_SIZE - 1);
    const float* p = partials + ((size_t)s * CHUNKS) * SLICE_SIZE + j;
    float sum = 0.0f;
#pragma unroll
    for (int g = 0; g < CHUNKS; ++g) sum += p[(size_t)g * SLICE_SIZE];
    out[i] = sum + Pb[bp[i]];
}

// ---------------- last-resort fallbacks ----------------
__global__ __launch_bounds__(256) void bias_init_kernel(const float* __restrict__ Pb,
                                                        const int* __restrict__ bp,
                                                        float* __restrict__ out, int n) {
    int i = blockIdx.x * 256 + threadIdx.x;
    if (i < n) out[i] = Pb[bp[i]];
}

__global__ __launch_bounds__(256) void edge_scatter_kernel(const float* __restrict__ x,
                                                           const float* __restrict__ PW,
                                                           const int* __restrict__ rows,
                                                           const int* __restrict__ cols,
                                                           const int* __restrict__ params,
                                                           float* __restrict__ out, int E) {
    int e = blockIdx.x * 256 + threadIdx.x;
    if (e < E) atomicAdd(out + rows[e], PW[params[e]] * x[cols[e]]);
}

extern "C" void kernel_launch(void* const* d_in, const int* in_sizes, int n_in,
                              void* d_out, int out_size, void* d_ws, size_t ws_size,
                              hipStream_t stream) {
    const float* x        = (const float*)d_in[0];
    const float* Param_W  = (const float*)d_in[1];
    const float* Param_b  = (const float*)d_in[2];
    const int*   w_rows   = (const int*)d_in[3];
    const int*   w_cols   = (const int*)d_in[4];
    const int*   w_params = (const int*)d_in[5];
    const int*   b_params = (const int*)d_in[6];
    float* out = (float*)d_out;

    const int N_  = in_sizes[0];   // 262144
    const int NP_ = in_sizes[1];   // 1280
    const int E_  = in_sizes[3];   // 16777216
    const int e4  = E_ / 4;

    const size_t partial_bytes = (size_t)SLICES * CHUNKS * SLICE_SIZE * sizeof(float); // 32 MiB
    const size_t vals_bytes    = (size_t)E_ * sizeof(float);                            // 64 MiB

    const bool base_ok = (N_ == SLICES * SLICE_SIZE) && (NP_ <= NPARAMS_MAX);

    // fused single-pass path
    const bool fused_ok = base_ok && (e4 % CHUNKS == 0) &&
                          ((e4 / CHUNKS) % (SCAN_THREADS * 2 * FSB) == 0);
    // R9 two-pass path
    const bool full_ok = base_ok && (E_ % (4 * 256 * VB) == 0) &&
                         (E_ % (4 * CHUNKS * SCAN_THREADS * 2 * SB4) == 0);

    if (fused_ok && ws_size >= partial_bytes) {
        float* partials = (float*)d_ws;
        const int e4_per_chunk = e4 / CHUNKS;   // 131072
        fused_scan_kernel<<<SLICES * CHUNKS, SCAN_THREADS, 0, stream>>>(
            x, Param_W, (const int4*)w_rows, (const int4*)w_cols,
            (const int4*)w_params, partials, e4_per_chunk);
        reduce_bias_kernel<<<(N_ + 255) / 256, 256, 0, stream>>>(
            partials, Param_b, b_params, out, N_);
    } else if (full_ok && ws_size >= vals_bytes + partial_bytes) {
        float*  vals     = (float*)d_ws;
        float*  partials = (float*)((char*)d_ws + vals_bytes);
        const int e4_per_chunk = e4 / CHUNKS;
        val_kernel<<<e4 / (256 * VB), 256, 0, stream>>>(
            x, Param_W, NP_, (const int4*)w_cols, (const int4*)w_params, (v4f*)vals);
        scan4_kernel<<<SLICES * CHUNKS, SCAN_THREADS, 0, stream>>>(
            (const int4*)w_rows, (const float4*)vals, partials, e4_per_chunk);
        reduce_bias_kernel<<<(N_ + 255) / 256, 256, 0, stream>>>(
            partials, Param_b, b_params, out, N_);
    } else {
        bias_init_kernel<<<(N_ + 255) / 256, 256, 0, stream>>>(Param_b, b_params, out, N_);
        edge_scatter_kernel<<<(E_ + 255) / 256, 256, 0, stream>>>(
            x, Param_W, w_rows, w_cols, w_params, out, E_);
    }
}